// Round 5
// baseline (509.183 us; speedup 1.0000x reference)
//
#include <hip/hip_runtime.h>

// Attn_Pred_Model: 8-tap decayed shift-sum along S + biases, masked.
// x: [16,16,4096,64] fp32. Analytic mask/arange2, masked-lane skip,
// chunked register loads, plain stores, plane-fastest block decode.
//
// Round 5 = Round 4 resubmission (R4 bench died on container infra, no
// counters). QUAD-PACKED WORK ASSIGNMENT (lane densification):
// R3's null showed wave runtime = max over lanes: any wave with >=1
// active lane-column runs full duration, and ~all waves had one ->
// ~31 full-duration waves/plane at only ~52% lane density. Repack:
// plane = 512 quads (32-row strip x 16 cols = 4 lanes, 64B segments,
// still coalesced). Compute quads (c < ceil(q/16), s>=128): 316/plane,
// enumerated first; pure-zero quads: 196/plane, after. Full-duration
// waves: ~31 -> ~20 per plane at 80% density; zero quads become dense
// store-only waves. Dead lanes (jb>=q) still early-exit, so FETCH is
// unchanged.
//
// Analytic identities (S=4096, BUCKET=64, BUCKETS_MIN=2):
//   arange2[s,j] = ((s>>6) - j) & 63
//   mask[s,j]    = (s >= 128) && (j < s>>6)
// q = s>>6 is strip-constant (strips are 32 rows, 32-aligned).
//
// Quad bookkeeping per plane (strips k in [0,124), s0 = 128+32k,
// q = 2+(k>>1), n(k) = ceil(q/16)):
//   k in [0,28):   q in [2,15],  n=1   -> 28 compute quads
//   k in [28,60):  q in [16,31], n=2   -> 64
//   k in [60,92):  q in [32,47], n=3   -> 96
//   k in [92,124): q in [48,63], n=4   -> 128   (total 316)
// zero quads: rows<128 (4 strips x 4 = 16) + per-band (4-n)*strips:
// 84 + 64 + 32 = 180, +16 = 196.  316 + 196 = 512 = 128 strips * 4. ✓

#define S_DIM 4096
#define PAST 8
#define RROWS 32                      // rows per thread
#define CHUNK 8                       // rows per load batch (= PAST)
#define PLANES 256                    // 16*16

typedef float v4f __attribute__((ext_vector_type(4)));

// Compute+store CHUNK rows. W = previous 8 rows (window), C = this chunk's
// 8 rows. Row dd of the chunk needs C[0..dd-1] and W[dd..7]; all indices
// are compile-time after unroll, so A/B stay in registers (no scratch).
#define DO_CHUNK(W, C, rbase)                                               \
    {                                                                       \
        _Pragma("unroll")                                                   \
        for (int dd = 0; dd < CHUNK; ++dd) {                                \
            v4f acc = cf[0] * ((dd - 1 >= 0) ? C[dd - 1] : W[CHUNK + dd - 1]); \
            _Pragma("unroll")                                               \
            for (int i = 1; i < PAST; ++i) {                                \
                const int idx = dd - 1 - i;                                 \
                acc += cf[i] * ((idx >= 0) ? C[idx] : W[CHUNK + idx]);      \
            }                                                               \
            op[((rbase) + dd) * 16 + f4] = (acc + bias) * mk;               \
        }                                                                   \
    }

__global__ __launch_bounds__(256) void attn_pred_kernel(
    const float* __restrict__ x,
    const float* __restrict__ pb_fwd,
    const float* __restrict__ pb_bwd,
    const float* __restrict__ alpha_p,
    const float* __restrict__ beta_p,
    float* __restrict__ out)
{
    const int bh = blockIdx.x & (PLANES - 1); // plane: FASTEST-varying
    const int b  = blockIdx.x >> 8;           // block slot within plane [0,8)
    const int T  = (b << 8) | threadIdx.x;    // flat thread within plane [0,2048)
    const int t  = T >> 2;                    // quad id [0,512)
    const int d  = T & 3;                     // lane within quad [0,4)

    // Decode quad id -> (strip base s0, colquad c).
    int s0, c;
    if (t < 316) {                            // compute quads (by q-band)
        if (t < 28)       { s0 = 128 + (t << 5);                 c = 0; }
        else if (t < 92)  { const unsigned u = t - 28;
                            s0 = 128 + ((28 + (u >> 1)) << 5);   c = u & 1; }
        else if (t < 188) { const unsigned u = t - 92;
                            const unsigned k3 = u / 3u;          // magic-mul
                            s0 = 128 + ((60 + k3) << 5);         c = u - 3u * k3; }
        else              { const unsigned u = t - 188;
                            s0 = 128 + ((92 + (u >> 2)) << 5);   c = u & 3; }
    } else {                                  // zero quads
        const int zt = t - 316;
        if (zt < 16)       { s0 = (zt >> 2) << 5;                c = zt & 3; }
        else if (zt < 100) { const unsigned u = zt - 16;
                             const unsigned k3 = u / 3u;
                             s0 = 128 + (k3 << 5);               c = 1 + (u - 3u * k3); }
        else if (zt < 164) { const unsigned u = zt - 100;
                             s0 = 128 + ((28 + (u >> 1)) << 5);  c = 2 + (u & 1); }
        else               { const unsigned u = zt - 164;
                             s0 = 128 + ((60 + u) << 5);         c = 3; }
    }

    const int q  = s0 >> 6;                   // strip-constant bucket row
    const int f4 = (c << 2) | d;              // float4 index within row [0,16)
    const int jb = f4 << 2;                   // first column of this thread

    const size_t plane = (size_t)bh * (S_DIM * 16);   // in v4f units
    const v4f* __restrict__ xp = (const v4f*)x + plane;
    v4f* __restrict__       op = (v4f*)out + plane;

    // Zero path: zero quads have s0<128 or jb >= q (since 16c >= q there),
    // so this single guard covers zero quads AND dead lanes of partial quads.
    if (s0 < 128 || jb >= q) {
        const v4f z = (v4f){0.f, 0.f, 0.f, 0.f};
        #pragma unroll
        for (int r = 0; r < RROWS; ++r)
            op[(s0 + r) * 16 + f4] = z;
        return;
    }

    // s0 >= 128 here, so the window preload needs no s<0 guard.
    const float alpha = alpha_p[0];
    const float beta  = beta_p[0];
    float cf[PAST];
    cf[0] = alpha;
    #pragma unroll
    for (int i = 1; i < PAST; ++i) cf[i] = cf[i - 1] * beta;

    const v4f bf = ((const v4f*)pb_fwd)[f4];
    v4f bias;
    bias.x = bf.x + pb_bwd[(q - jb    ) & 63];
    bias.y = bf.y + pb_bwd[(q - jb - 1) & 63];
    bias.z = bf.z + pb_bwd[(q - jb - 2) & 63];
    bias.w = bf.w + pb_bwd[(q - jb - 3) & 63];

    v4f mk;
    mk.x = 1.f;                               // jb < q guaranteed here
    mk.y = (jb + 1 < q) ? 1.f : 0.f;
    mk.z = (jb + 2 < q) ? 1.f : 0.f;
    mk.w = (jb + 3 < q) ? 1.f : 0.f;

    // Chunked loads: 8 independent row-loads issued back-to-back per batch.
    v4f A[CHUNK], B[CHUNK];

    #pragma unroll
    for (int k = 0; k < CHUNK; ++k)           // window: rows s0-8..s0-1
        A[k] = xp[(s0 - PAST + k) * 16 + f4];

    #pragma unroll
    for (int k = 0; k < CHUNK; ++k)           // chunk 0: rows s0..s0+7
        B[k] = xp[(s0 + k) * 16 + f4];
    DO_CHUNK(A, B, s0)

    #pragma unroll
    for (int k = 0; k < CHUNK; ++k)           // chunk 1
        A[k] = xp[(s0 + CHUNK + k) * 16 + f4];
    DO_CHUNK(B, A, s0 + CHUNK)

    #pragma unroll
    for (int k = 0; k < CHUNK; ++k)           // chunk 2
        B[k] = xp[(s0 + 2 * CHUNK + k) * 16 + f4];
    DO_CHUNK(A, B, s0 + 2 * CHUNK)

    #pragma unroll
    for (int k = 0; k < CHUNK; ++k)           // chunk 3
        A[k] = xp[(s0 + 3 * CHUNK + k) * 16 + f4];
    DO_CHUNK(B, A, s0 + 3 * CHUNK)
}

extern "C" void kernel_launch(void* const* d_in, const int* in_sizes, int n_in,
                              void* d_out, int out_size, void* d_ws, size_t ws_size,
                              hipStream_t stream) {
    const float* x       = (const float*)d_in[0];
    const float* pb_fwd  = (const float*)d_in[1];
    const float* pb_bwd  = (const float*)d_in[2];
    const float* alpha_p = (const float*)d_in[3];
    const float* beta_p  = (const float*)d_in[4];
    // d_in[5] = arange2 (int64), d_in[6] = mask -- both computed analytically
    float* out = (float*)d_out;

    const int grid = PLANES * 8;  // 2048 blocks x 256 threads
    attn_pred_kernel<<<grid, 256, 0, stream>>>(x, pb_fwd, pb_bwd, alpha_p,
                                               beta_p, out);
}